// Round 10
// baseline (242.943 us; speedup 1.0000x reference)
//
#include <hip/hip_runtime.h>
#include <stdint.h>

#define AS1 __attribute__((address_space(1)))
#define AS3 __attribute__((address_space(3)))

typedef __bf16 bf16x8 __attribute__((ext_vector_type(8)));
typedef float f32x4 __attribute__((ext_vector_type(4)));

constexpr int NB = 8;     // batches
constexpr int N  = 2048;  // nodes
constexpr int F  = 128;   // features (in == out)

__device__ __forceinline__ unsigned short bf16r(float f) {
    unsigned u = __float_as_uint(f);
    return (unsigned short)((u + 0x7FFFu + ((u >> 16) & 1u)) >> 16);
}
__device__ __forceinline__ float bf2f(unsigned short s) {
    return __uint_as_float(((unsigned)s) << 16);
}

// ---------------------------------------------------------------------------
// Wb2 element layout (MFMA-B-operand native, linear in k-chunks):
//   byte(b, n, o) = b*N*F*2 + (n>>3)*2048 + o*16 + (n&7)*2
// BK=64 chunk c of batch b = the contiguous 16384 B at  b*N*F*2 + c*16384.
// ---------------------------------------------------------------------------

// K1 (fused): Wh = h @ W^T;  e = Wh @ a2;  p = exp(e);
//   p16 = bf16(p);  Wb2 = bf16(bf2f(p16) * Wh)
__global__ __launch_bounds__(256) void k1_wh(const float* __restrict__ h,
                                             const float* __restrict__ W,
                                             const float* __restrict__ a,
                                             unsigned short* __restrict__ Wb2,
                                             unsigned short* __restrict__ p16) {
    __shared__ float epart[2][64];

    const int tid  = threadIdx.x;
    const int lane = tid & 63, wid = tid >> 6;
    const int quad = lane >> 4, l15 = lane & 15;
    const int wm = wid >> 1, wn = wid & 1;
    const int m0 = blockIdx.x * 64;
    const int batch = m0 >> 11;
    const int nbase = m0 & 2047;

    f32x4 acc[2][4] = {};

#pragma unroll
    for (int kk = 0; kk < 4; ++kk) {
        const int k = kk * 32 + quad * 8;
        bf16x8 afr[2], bfr[4];
#pragma unroll
        for (int rt = 0; rt < 2; ++rt) {
            const float* src = h + (size_t)(m0 + wm * 32 + rt * 16 + l15) * F + k;
            float4 x0 = *(const float4*)src;
            float4 x1 = *(const float4*)(src + 4);
            afr[rt][0] = (__bf16)x0.x; afr[rt][1] = (__bf16)x0.y;
            afr[rt][2] = (__bf16)x0.z; afr[rt][3] = (__bf16)x0.w;
            afr[rt][4] = (__bf16)x1.x; afr[rt][5] = (__bf16)x1.y;
            afr[rt][6] = (__bf16)x1.z; afr[rt][7] = (__bf16)x1.w;
        }
#pragma unroll
        for (int ct = 0; ct < 4; ++ct) {
            const int o = wn * 64 + ct * 16 + l15;
            const float* src = W + (size_t)o * F + k;
            float4 x0 = *(const float4*)src;
            float4 x1 = *(const float4*)(src + 4);
            bfr[ct][0] = (__bf16)x0.x; bfr[ct][1] = (__bf16)x0.y;
            bfr[ct][2] = (__bf16)x0.z; bfr[ct][3] = (__bf16)x0.w;
            bfr[ct][4] = (__bf16)x1.x; bfr[ct][5] = (__bf16)x1.y;
            bfr[ct][6] = (__bf16)x1.z; bfr[ct][7] = (__bf16)x1.w;
        }
#pragma unroll
        for (int rt = 0; rt < 2; ++rt)
#pragma unroll
            for (int ct = 0; ct < 4; ++ct)
                acc[rt][ct] = __builtin_amdgcn_mfma_f32_16x16x32_bf16(
                    afr[rt], bfr[ct], acc[rt][ct], 0, 0, 0);
    }

    float a2v[4];
#pragma unroll
    for (int ct = 0; ct < 4; ++ct) a2v[ct] = a[F + wn * 64 + ct * 16 + l15];

    float ep[2][4];
#pragma unroll
    for (int rt = 0; rt < 2; ++rt)
#pragma unroll
        for (int g = 0; g < 4; ++g) {
            float s = 0.f;
#pragma unroll
            for (int ct = 0; ct < 4; ++ct) s += acc[rt][ct][g] * a2v[ct];
            ep[rt][g] = s;
        }
#pragma unroll
    for (int m = 1; m < 16; m <<= 1)
#pragma unroll
        for (int rt = 0; rt < 2; ++rt)
#pragma unroll
            for (int g = 0; g < 4; ++g)
                ep[rt][g] += __shfl_xor(ep[rt][g], m);

    if (l15 == 0)
#pragma unroll
        for (int rt = 0; rt < 2; ++rt)
#pragma unroll
            for (int g = 0; g < 4; ++g)
                epart[wn][wm * 32 + rt * 16 + quad * 4 + g] = ep[rt][g];
    __syncthreads();

#pragma unroll
    for (int rt = 0; rt < 2; ++rt)
#pragma unroll
        for (int ct = 0; ct < 4; ++ct) {
            const int o  = wn * 64 + ct * 16 + l15;
            const int r0 = wm * 32 + rt * 16 + quad * 4;
            const int n0 = nbase + r0;
            ushort4 v;
#pragma unroll
            for (int g = 0; g < 4; ++g) {
                const float e  = epart[0][r0 + g] + epart[1][r0 + g];
                const float pf = bf2f(bf16r(expf(e)));
                (&v.x)[g] = bf16r(pf * acc[rt][ct][g]);
            }
            size_t off = (size_t)batch * N * F + (size_t)(n0 >> 3) * 1024 + o * 8 + (n0 & 7);
            *(ushort4*)&Wb2[off] = v;
        }

    if (tid < 64) {
        const float e = epart[0][tid] + epart[1][tid];
        p16[batch * N + nbase + tid] = bf16r(expf(e));
    }
}

// K3: out[b][i][o] = (sum_j adj[b][i][j] * Wb2[j][o]) / (sum_j adj * p[j])
// Non-draining 3-buffer pipeline: all K-loop VMEM is LDS-DMA (5 uniform
// instr/wave/chunk), raw s_barrier + hand s_waitcnt vmcnt(5) so stage(c+1)
// stays in flight ACROSS the barrier; each stage gets 2 chunk periods.
// p pre-staged to LDS once (keeps vmcnt bookkeeping exact).
// Tile 16(i) x 128(o), 4 waves (o-slice 32/wave), BK=64, LDS 64 KB ->
// 2 blocks/CU at grid 1024. XCD-pin: batch = blockIdx&7.
__global__ __launch_bounds__(256) void k3_attn(const float* __restrict__ adj,
                                               const unsigned short* __restrict__ Wb2,
                                               const unsigned short* __restrict__ p16,
                                               float* __restrict__ out) {
    __shared__ __align__(16) float          At[3][16 * 64];    // 4 KB each
    __shared__ __align__(16) unsigned short Bt[3][8 * 1024];   // 16 KB each
    __shared__ __align__(16) unsigned short Pt[2048];          // 4 KB

    const int tid  = threadIdx.x;
    const int lane = tid & 63, wid = tid >> 6;
    const int quad = lane >> 4, l15 = lane & 15;
    const int b  = blockIdx.x & 7;
    const int i0 = (blockIdx.x >> 3) * 16;

    // A staging: 1 instr/wave covers rows ri = wid*4 .. +3 (256 B each).
    // Slot lslot in row ri holds global 16B-chunk lslot^ri (XOR swizzle).
    const int ri = wid * 4 + (lane >> 4);
    const int lslot = lane & 15;
    const float* aSrc = adj + (size_t)b * N * N + (size_t)(i0 + ri) * N
                      + ((lslot ^ ri) << 2);
    // B staging: linear copy, 4 instr/wave (wave covers bytes wid*4K..+4K).
    const char* bSrc = (const char*)Wb2 + (size_t)b * N * F * 2
                     + (size_t)wid * 4096 + lane * 16;
    // p staging: whole batch row (4 KB), 1 instr/wave, once.
    const char* pSrc = (const char*)p16 + (size_t)b * N * 2
                     + (size_t)wid * 1024 + lane * 16;

    auto stage = [&](int buf, int c) {
        __builtin_amdgcn_global_load_lds((const AS1 void*)(aSrc + c * 64),
            (AS3 void*)((char*)&At[buf][0] + wid * 1024), 16, 0, 0);
#pragma unroll
        for (int s = 0; s < 4; ++s)
            __builtin_amdgcn_global_load_lds(
                (const AS1 void*)(bSrc + (size_t)c * 16384 + s * 1024),
                (AS3 void*)((char*)&Bt[buf][0] + wid * 4096 + s * 1024), 16, 0, 0);
    };

    f32x4 acc[2] = {};
    f32x4 dacc = {};

    // prologue: p (1) + stage(0) (5) + stage(1) (5) in flight = 11
    __builtin_amdgcn_global_load_lds((const AS1 void*)pSrc,
        (AS3 void*)((char*)&Pt[0] + wid * 1024), 16, 0, 0);
    stage(0, 0);
    stage(1, 1);

    // Per iter c: wait vmcnt(5) -> own stage(c) (and p, first iter) retired,
    // stage(c+1) still flying; s_barrier -> ALL waves' stage(c) done; issue
    // stage(c+2) into buf (c+2)%3 (safe: its ds_reads finished pre-barrier);
    // compute(c). vmcnt never reaches 0 until the tail.
#define BODY(C, BUF, DOSTAGE, VMSTR) do {                                     \
    asm volatile("s_waitcnt " VMSTR ::: "memory");                            \
    asm volatile("s_barrier" ::: "memory");                                   \
    if (DOSTAGE) stage(((BUF) + 2) % 3, (C) + 2);                             \
    _Pragma("unroll")                                                         \
    for (int ks = 0; ks < 2; ++ks) {                                          \
        const char* rowb = (const char*)&At[BUF][0] + l15 * 256;              \
        const int g0 = ks * 8 + quad * 2;                                     \
        f32x4 x0 = *(const f32x4*)(rowb + ((g0 ^ l15) << 4));                 \
        f32x4 x1 = *(const f32x4*)(rowb + (((g0 + 1) ^ l15) << 4));           \
        const char* bb = (const char*)&Bt[BUF][0]                             \
                       + (ks * 4 + quad) * 2048 + wid * 512 + l15 * 16;       \
        bf16x8 b0 = *(const bf16x8*)bb;                                       \
        bf16x8 b1 = *(const bf16x8*)(bb + 256);                               \
        bf16x8 pv = *(const bf16x8*)((const char*)&Pt[0]                      \
                       + (C) * 128 + ks * 64 + quad * 16);                    \
        bf16x8 af;                                                            \
        af[0] = (__bf16)x0[0]; af[1] = (__bf16)x0[1];                         \
        af[2] = (__bf16)x0[2]; af[3] = (__bf16)x0[3];                         \
        af[4] = (__bf16)x1[0]; af[5] = (__bf16)x1[1];                         \
        af[6] = (__bf16)x1[2]; af[7] = (__bf16)x1[3];                         \
        acc[0] = __builtin_amdgcn_mfma_f32_16x16x32_bf16(af, b0, acc[0], 0, 0, 0); \
        acc[1] = __builtin_amdgcn_mfma_f32_16x16x32_bf16(af, b1, acc[1], 0, 0, 0); \
        dacc   = __builtin_amdgcn_mfma_f32_16x16x32_bf16(af, pv, dacc, 0, 0, 0);   \
    }                                                                         \
} while (0)

    for (int c0 = 0; c0 < 30; c0 += 3) {
        BODY(c0 + 0, 0, 1, "vmcnt(5)");
        BODY(c0 + 1, 1, 1, "vmcnt(5)");
        BODY(c0 + 2, 2, 1, "vmcnt(5)");
    }
    BODY(30, 0, 0, "vmcnt(5)");
    BODY(31, 1, 0, "vmcnt(0)");
#undef BODY

    // dacc reg g = denom for row quad*4+g — same row mapping as acc.
    float inv[4];
#pragma unroll
    for (int g = 0; g < 4; ++g) inv[g] = 1.0f / dacc[g];

    float* ob = out + (size_t)b * N * F;
#pragma unroll
    for (int ct = 0; ct < 2; ++ct) {
        const int o = wid * 32 + ct * 16 + l15;
#pragma unroll
        for (int g = 0; g < 4; ++g) {
            const int i = i0 + quad * 4 + g;
            ob[(size_t)i * F + o] = acc[ct][g] * inv[g];
        }
    }
}

// ---------------------------------------------------------------------------
extern "C" void kernel_launch(void* const* d_in, const int* in_sizes, int n_in,
                              void* d_out, int out_size, void* d_ws, size_t ws_size,
                              hipStream_t stream) {
    const float* h   = (const float*)d_in[0];
    const float* adj = (const float*)d_in[1];
    const float* W   = (const float*)d_in[2];
    const float* a   = (const float*)d_in[3];
    float* out = (float*)d_out;

    unsigned short* Wb2 = (unsigned short*)d_ws;                          // 4 MB
    unsigned short* p16 = (unsigned short*)((char*)d_ws + (4u << 20));    // 32 KB

    k1_wh<<<NB * N / 64, 256, 0, stream>>>(h, W, a, Wb2, p16);
    k3_attn<<<NB * (N / 16), 256, 0, stream>>>(adj, Wb2, p16, out);
}

// Round 11
// 218.874 us; speedup vs baseline: 1.1100x; 1.1100x over previous
//
#include <hip/hip_runtime.h>
#include <stdint.h>

#define AS1 __attribute__((address_space(1)))
#define AS3 __attribute__((address_space(3)))

typedef __bf16 bf16x8 __attribute__((ext_vector_type(8)));
typedef float f32x4 __attribute__((ext_vector_type(4)));

constexpr int NB = 8;     // batches
constexpr int N  = 2048;  // nodes
constexpr int F  = 128;   // features (in == out)

__device__ __forceinline__ unsigned short bf16r(float f) {
    unsigned u = __float_as_uint(f);
    return (unsigned short)((u + 0x7FFFu + ((u >> 16) & 1u)) >> 16);
}
__device__ __forceinline__ float bf2f(unsigned short s) {
    return __uint_as_float(((unsigned)s) << 16);
}

// ---------------------------------------------------------------------------
// Wb2 element layout (MFMA-B-operand native, linear in k-chunks):
//   byte(b, n, o) = b*N*F*2 + (n>>3)*2048 + o*16 + (n&7)*2
// BK=64 chunk c of batch b = the contiguous 16384 B at  b*N*F*2 + c*16384.
// ---------------------------------------------------------------------------

// K1 (fused): Wh = h @ W^T;  e = Wh @ a2;  p = exp(e);
//   p16 = bf16(p);  Wb2 = bf16(bf2f(p16) * Wh)
__global__ __launch_bounds__(256) void k1_wh(const float* __restrict__ h,
                                             const float* __restrict__ W,
                                             const float* __restrict__ a,
                                             unsigned short* __restrict__ Wb2,
                                             unsigned short* __restrict__ p16) {
    __shared__ float epart[2][64];

    const int tid  = threadIdx.x;
    const int lane = tid & 63, wid = tid >> 6;
    const int quad = lane >> 4, l15 = lane & 15;
    const int wm = wid >> 1, wn = wid & 1;
    const int m0 = blockIdx.x * 64;
    const int batch = m0 >> 11;
    const int nbase = m0 & 2047;

    f32x4 acc[2][4] = {};

#pragma unroll
    for (int kk = 0; kk < 4; ++kk) {
        const int k = kk * 32 + quad * 8;
        bf16x8 afr[2], bfr[4];
#pragma unroll
        for (int rt = 0; rt < 2; ++rt) {
            const float* src = h + (size_t)(m0 + wm * 32 + rt * 16 + l15) * F + k;
            float4 x0 = *(const float4*)src;
            float4 x1 = *(const float4*)(src + 4);
            afr[rt][0] = (__bf16)x0.x; afr[rt][1] = (__bf16)x0.y;
            afr[rt][2] = (__bf16)x0.z; afr[rt][3] = (__bf16)x0.w;
            afr[rt][4] = (__bf16)x1.x; afr[rt][5] = (__bf16)x1.y;
            afr[rt][6] = (__bf16)x1.z; afr[rt][7] = (__bf16)x1.w;
        }
#pragma unroll
        for (int ct = 0; ct < 4; ++ct) {
            const int o = wn * 64 + ct * 16 + l15;
            const float* src = W + (size_t)o * F + k;
            float4 x0 = *(const float4*)src;
            float4 x1 = *(const float4*)(src + 4);
            bfr[ct][0] = (__bf16)x0.x; bfr[ct][1] = (__bf16)x0.y;
            bfr[ct][2] = (__bf16)x0.z; bfr[ct][3] = (__bf16)x0.w;
            bfr[ct][4] = (__bf16)x1.x; bfr[ct][5] = (__bf16)x1.y;
            bfr[ct][6] = (__bf16)x1.z; bfr[ct][7] = (__bf16)x1.w;
        }
#pragma unroll
        for (int rt = 0; rt < 2; ++rt)
#pragma unroll
            for (int ct = 0; ct < 4; ++ct)
                acc[rt][ct] = __builtin_amdgcn_mfma_f32_16x16x32_bf16(
                    afr[rt], bfr[ct], acc[rt][ct], 0, 0, 0);
    }

    float a2v[4];
#pragma unroll
    for (int ct = 0; ct < 4; ++ct) a2v[ct] = a[F + wn * 64 + ct * 16 + l15];

    float ep[2][4];
#pragma unroll
    for (int rt = 0; rt < 2; ++rt)
#pragma unroll
        for (int g = 0; g < 4; ++g) {
            float s = 0.f;
#pragma unroll
            for (int ct = 0; ct < 4; ++ct) s += acc[rt][ct][g] * a2v[ct];
            ep[rt][g] = s;
        }
#pragma unroll
    for (int m = 1; m < 16; m <<= 1)
#pragma unroll
        for (int rt = 0; rt < 2; ++rt)
#pragma unroll
            for (int g = 0; g < 4; ++g)
                ep[rt][g] += __shfl_xor(ep[rt][g], m);

    if (l15 == 0)
#pragma unroll
        for (int rt = 0; rt < 2; ++rt)
#pragma unroll
            for (int g = 0; g < 4; ++g)
                epart[wn][wm * 32 + rt * 16 + quad * 4 + g] = ep[rt][g];
    __syncthreads();

#pragma unroll
    for (int rt = 0; rt < 2; ++rt)
#pragma unroll
        for (int ct = 0; ct < 4; ++ct) {
            const int o  = wn * 64 + ct * 16 + l15;
            const int r0 = wm * 32 + rt * 16 + quad * 4;
            const int n0 = nbase + r0;
            ushort4 v;
#pragma unroll
            for (int g = 0; g < 4; ++g) {
                const float e  = epart[0][r0 + g] + epart[1][r0 + g];
                const float pf = bf2f(bf16r(expf(e)));
                (&v.x)[g] = bf16r(pf * acc[rt][ct][g]);
            }
            size_t off = (size_t)batch * N * F + (size_t)(n0 >> 3) * 1024 + o * 8 + (n0 & 7);
            *(ushort4*)&Wb2[off] = v;
        }

    if (tid < 64) {
        const float e = epart[0][tid] + epart[1][tid];
        p16[batch * N + nbase + tid] = bf16r(expf(e));
    }
}

// K3: out[b][i][o] = (sum_j adj[b][i][j] * Wb2[j][o]) / (sum_j adj * p[j])
// R9-proven dbuf cadence (barrier | stage(c+1) | compute(c)), i-tile DOUBLED
// to 32 rows to halve B staging traffic (512 -> 256 MB total; period is
// staging-service-time-bound at the CU port). 4 waves as 2x2, wave 16x64,
// BK=64. A dbuf 8 KB (XOR-swizzled), B dbuf 16 KB (linear), p once 4 KB:
// LDS 52 KB. Grid 512 = 2 blocks/CU; XCD-pin batch = blockIdx&7.
__global__ __launch_bounds__(256) void k3_attn(const float* __restrict__ adj,
                                               const unsigned short* __restrict__ Wb2,
                                               const unsigned short* __restrict__ p16,
                                               float* __restrict__ out) {
    __shared__ __align__(16) float          At[2][32 * 64];    // 8 KB each
    __shared__ __align__(16) unsigned short Bt[2][8 * 1024];   // 16 KB each
    __shared__ __align__(16) unsigned short Pt[2048];          // 4 KB

    const int tid  = threadIdx.x;
    const int lane = tid & 63, wid = tid >> 6;
    const int quad = lane >> 4, l15 = lane & 15;
    const int wm = wid >> 1, wn = wid & 1;
    const int b  = blockIdx.x & 7;
    const int i0 = (blockIdx.x >> 3) * 32;

    // A staging: 8 KB/chunk = 8 instr (2/wave). Instr (wid,s) fills rows
    // (wid*2+s)*4 .. +3. Lane: row ri = instr*4 + (lane>>4); slot lslot =
    // lane&15 holds global 16B-chunk lslot^(ri&15) (XOR swizzle).
    const int lslot = lane & 15;
    const float* aSrcs[2];
#pragma unroll
    for (int s = 0; s < 2; ++s) {
        const int ri = (wid * 2 + s) * 4 + (lane >> 4);
        aSrcs[s] = adj + (size_t)b * N * N + (size_t)(i0 + ri) * N
                 + ((lslot ^ (ri & 15)) << 2);
    }
    // B staging: linear copy, 4 instr/wave (wave covers bytes wid*4K..+4K).
    const char* bSrc = (const char*)Wb2 + (size_t)b * N * F * 2
                     + (size_t)wid * 4096 + lane * 16;
    // p staging: whole batch row (4 KB), 1 instr/wave, once.
    const char* pSrc = (const char*)p16 + (size_t)b * N * 2
                     + (size_t)wid * 1024 + lane * 16;

    auto stage = [&](int buf, int c) {
#pragma unroll
        for (int s = 0; s < 2; ++s)
            __builtin_amdgcn_global_load_lds((const AS1 void*)(aSrcs[s] + c * 64),
                (AS3 void*)((char*)&At[buf][0] + (wid * 2 + s) * 1024), 16, 0, 0);
#pragma unroll
        for (int s = 0; s < 4; ++s)
            __builtin_amdgcn_global_load_lds(
                (const AS1 void*)(bSrc + (size_t)c * 16384 + s * 1024),
                (AS3 void*)((char*)&Bt[buf][0] + wid * 4096 + s * 1024), 16, 0, 0);
    };

    f32x4 acc[4] = {};
    f32x4 dacc = {};

    // prologue
    __builtin_amdgcn_global_load_lds((const AS1 void*)pSrc,
        (AS3 void*)((char*)&Pt[0] + wid * 1024), 16, 0, 0);
    stage(0, 0);

    for (int c = 0; c < 32; ++c) {
        const int cur = c & 1;
        __syncthreads();              // drains stage(c) (+p first time)
        if (c + 1 < 32) stage(cur ^ 1, c + 1);

#pragma unroll
        for (int ks = 0; ks < 2; ++ks) {
            // A frag: row wm*16+l15, global chunks g0 = ks*8+quad*2, g0+1
            const char* rowb = (const char*)&At[cur][0] + (wm * 16 + l15) * 256;
            const int g0 = ks * 8 + quad * 2;
            f32x4 x0 = *(const f32x4*)(rowb + ((g0 ^ l15) << 4));
            f32x4 x1 = *(const f32x4*)(rowb + (((g0 + 1) ^ l15) << 4));
            // B frags (linear image): k-group = ks*4+quad, o = wn*64+ct*16+l15
            const char* bb = (const char*)&Bt[cur][0]
                           + (ks * 4 + quad) * 2048 + wn * 1024 + l15 * 16;
            bf16x8 b0 = *(const bf16x8*)bb;
            bf16x8 b1 = *(const bf16x8*)(bb + 256);
            bf16x8 b2 = *(const bf16x8*)(bb + 512);
            bf16x8 b3 = *(const bf16x8*)(bb + 768);
            bf16x8 pv = *(const bf16x8*)((const char*)&Pt[0]
                           + c * 128 + ks * 64 + quad * 16);

            bf16x8 af;   // adj in {0,1}: cvt exact; p folded into B
            af[0] = (__bf16)x0[0]; af[1] = (__bf16)x0[1];
            af[2] = (__bf16)x0[2]; af[3] = (__bf16)x0[3];
            af[4] = (__bf16)x1[0]; af[5] = (__bf16)x1[1];
            af[6] = (__bf16)x1[2]; af[7] = (__bf16)x1[3];

            acc[0] = __builtin_amdgcn_mfma_f32_16x16x32_bf16(af, b0, acc[0], 0, 0, 0);
            acc[1] = __builtin_amdgcn_mfma_f32_16x16x32_bf16(af, b1, acc[1], 0, 0, 0);
            acc[2] = __builtin_amdgcn_mfma_f32_16x16x32_bf16(af, b2, acc[2], 0, 0, 0);
            acc[3] = __builtin_amdgcn_mfma_f32_16x16x32_bf16(af, b3, acc[3], 0, 0, 0);
            dacc   = __builtin_amdgcn_mfma_f32_16x16x32_bf16(af, pv, dacc, 0, 0, 0);
        }
    }

    // dacc reg g = denom for row quad*4+g — same row mapping as acc.
    float inv[4];
#pragma unroll
    for (int g = 0; g < 4; ++g) inv[g] = 1.0f / dacc[g];

    float* ob = out + (size_t)b * N * F;
#pragma unroll
    for (int ct = 0; ct < 4; ++ct) {
        const int o = wn * 64 + ct * 16 + l15;
#pragma unroll
        for (int g = 0; g < 4; ++g) {
            const int i = i0 + wm * 16 + quad * 4 + g;
            ob[(size_t)i * F + o] = acc[ct][g] * inv[g];
        }
    }
}

// ---------------------------------------------------------------------------
extern "C" void kernel_launch(void* const* d_in, const int* in_sizes, int n_in,
                              void* d_out, int out_size, void* d_ws, size_t ws_size,
                              hipStream_t stream) {
    const float* h   = (const float*)d_in[0];
    const float* adj = (const float*)d_in[1];
    const float* W   = (const float*)d_in[2];
    const float* a   = (const float*)d_in[3];
    float* out = (float*)d_out;

    unsigned short* Wb2 = (unsigned short*)d_ws;                          // 4 MB
    unsigned short* p16 = (unsigned short*)((char*)d_ws + (4u << 20));    // 32 KB

    k1_wh<<<NB * N / 64, 256, 0, stream>>>(h, W, a, Wb2, p16);
    k3_attn<<<NB * (N / 32), 256, 0, stream>>>(adj, Wb2, p16, out);
}